// Round 6
// baseline (283.821 us; speedup 1.0000x reference)
//
#include <hip/hip_runtime.h>
#include <stdint.h>

#define E_N 16
#define HID 2048
#define INTER_D 4096
#define NPAIR 2048
#define NTOK 1024
#define CAP 256

typedef __attribute__((ext_vector_type(8))) short bf16x8;
typedef __attribute__((ext_vector_type(4))) float f32x4;

static __device__ __forceinline__ unsigned short f2bf(float f) {
  union { float f; unsigned int u; } x; x.f = f;
  unsigned int r = x.u + 0x7fffu + ((x.u >> 16) & 1u);
  return (unsigned short)(r >> 16);
}

// ---------------- routing: per-expert pair lists ----------------
__global__ void route_kernel(const int* __restrict__ idx, int* __restrict__ counts,
                             int* __restrict__ gidlist) {
  __shared__ int cnt[E_N];
  const int tid = threadIdx.x;
  if (tid < E_N) cnt[tid] = 0;
  for (int j = tid; j < E_N * CAP; j += 256) gidlist[j] = 0;  // pad with valid gid 0
  __syncthreads();
  for (int p = tid; p < NPAIR; p += 256) {
    int e = idx[p] & 15;
    int pos = atomicAdd(&cnt[e], 1);
    if (pos < CAP) gidlist[e * CAP + pos] = p;
  }
  __syncthreads();
  if (tid < E_N) counts[tid] = (cnt[tid] < CAP) ? cnt[tid] : CAP;
}

// ---------------- tokens fp32 -> bf16 ----------------
__global__ void prep_a_kernel(const float* __restrict__ tok, unsigned short* __restrict__ A1) {
  const int i = (blockIdx.x * 256 + threadIdx.x) * 4;
  const float4 v = *reinterpret_cast<const float4*>(tok + i);
  ushort4 o;
  o.x = f2bf(v.x); o.y = f2bf(v.y); o.z = f2bf(v.z); o.w = f2bf(v.w);
  *reinterpret_cast<ushort4*>(A1 + i) = o;
}

// ---------------- grouped GEMM: BM=256 x BN=256, BK=64, 16 waves (4Mx4N, 64x64/wave)
// MODE 0: h = bf16(relu(A1 @ w1 + b1))           KDT=2048, NDIM=4096, KSPLIT=1
// MODE 1: out += tw * (h @ w2 [+ b2 if kh==0])   KDT=4096, NDIM=2048, KSPLIT=2
// Grid = 256 blocks both (1/CU, single generation). LDS reads per B-byte = 4:1.
// Single B reg set: vmcnt(2) retire B(t+1) -> writeB -> reload regs with B(t+2).
template <int KDT, int NDIM, int MODE, int KSPLIT>
__global__ __launch_bounds__(1024, 4) void moe_gemm_kernel(
    const unsigned short* __restrict__ Asrc,  // bf16 rows, stride KDT
    const float* __restrict__ W,              // [E][KDT][NDIM] fp32
    const float* __restrict__ bias,           // [E][NDIM]
    const float* __restrict__ tw,             // [NPAIR] (MODE 1)
    const int* __restrict__ counts,
    const int* __restrict__ gidlist,
    unsigned short* __restrict__ Hout,        // MODE 0
    float* __restrict__ Oout) {               // MODE 1 (atomic)
  constexpr int KLOC = KDT / KSPLIT;          // 2048 both
  constexpr int NK = KLOC / 64;               // 32 both
  constexpr int NB = NDIM / 256;
  const int bid = blockIdx.x;
  const int e   = bid / (NB * KSPLIT);
  const int rem = bid % (NB * KSPLIT);
  const int nc  = rem / KSPLIT;
  const int kh  = rem % KSPLIT;
  const int ne = counts[e];
  if (ne <= 0) return;
  const int n0 = nc * 256;
  const int tid = threadIdx.x;
  const int lane = tid & 63;
  const int wv = tid >> 6;   // 0..15
  const int wm = wv >> 2;    // M group of 64 rows
  const int wn = wv & 3;     // N group of 64 cols

  extern __shared__ char smem[];
  char* Ab0 = smem;              // 2 x 32 KiB A (bf16 [256][64], source-swizzled)
  char* Ab1 = smem + 32768;
  char* Bs0 = smem + 65536;      // 2 x 32 KiB B (bf16 [256 n][64 k], swz-XOR units)
  char* Bs1 = smem + 98304;
  __shared__ int sgid[CAP];
  if (tid < CAP) sgid[tid] = gidlist[e * CAP + tid];
  __syncthreads();

  // ---- A staging (global_load_lds; dest linear, source pre-swizzled) ----
  const int c16 = (lane & 7) ^ ((lane >> 3) & 7);
  const unsigned short* arp[2];
#pragma unroll
  for (int i = 0; i < 2; ++i) {
    const int row = (wv * 2 + i) * 8 + (lane >> 3);
    const int gid = sgid[row];
    const long arow = (MODE == 0) ? (gid >> 1) : gid;
    arp[i] = Asrc + arow * (long)KDT + kh * KLOC + c16 * 8;
  }
  auto stageA = [&](int t, char* buf) {
#pragma unroll
    for (int i = 0; i < 2; ++i) {
      char* dst = buf + (wv * 2 + i) * 1024;
      __builtin_amdgcn_global_load_lds(
          (const __attribute__((address_space(1))) void*)(arp[i] + t * 64),
          (__attribute__((address_space(3))) void*)dst, 16, 0, 0);
    }
  };

  // ---- B staging: thread loads 4 k-rows x 4 n-cols fp32; packs to one b64/col ----
  // map: n = (wv&3)*64 + (lane&15)*4 + c ; k = (wv>>2)*16 + (lane>>4)*4 + r
  const int kbB = ((wv >> 2) * 16) + ((lane >> 4) * 4);
  const int nbB = (wv & 3) * 64 + (lane & 15) * 4;
  const float* wbase = W + ((long)e * KDT + (long)kh * KLOC) * NDIM + n0 + nbB;
  int bbyte[4];
#pragma unroll
  for (int c = 0; c < 4; ++c) {
    const int n = nbB + c;
    const int swz = ((n >> 2) ^ n) & 7;
    bbyte[c] = n * 128 + (((kbB >> 3) ^ swz) << 4) + (kbB & 4) * 2;
  }
  auto loadB = [&](int t, f32x4& r0, f32x4& r1, f32x4& r2, f32x4& r3) {
    const float* p = wbase + (long)(t * 64 + kbB) * NDIM;
    r0 = *reinterpret_cast<const f32x4*>(p);
    r1 = *reinterpret_cast<const f32x4*>(p + NDIM);
    r2 = *reinterpret_cast<const f32x4*>(p + 2 * NDIM);
    r3 = *reinterpret_cast<const f32x4*>(p + 3 * NDIM);
  };
  auto writeB = [&](char* Bb, const f32x4& r0, const f32x4& r1,
                    const f32x4& r2, const f32x4& r3) {
#pragma unroll
    for (int c = 0; c < 4; ++c) {
      unsigned long long lo = (unsigned)f2bf(r0[c]) | ((unsigned)f2bf(r1[c]) << 16);
      unsigned long long hi = (unsigned)f2bf(r2[c]) | ((unsigned)f2bf(r3[c]) << 16);
      *reinterpret_cast<unsigned long long*>(Bb + bbyte[c]) = lo | (hi << 32);
    }
  };

  // ---- fragment LDS byte offsets ----
  const int rl = lane & 15;
  const int kg = lane >> 4;  // 0..3
  int abyte[2], bbF[2][2];
#pragma unroll
  for (int ks = 0; ks < 2; ++ks) {
    const int unit = (ks * 4 + kg) ^ (lane & 7);
    abyte[ks] = (wm * 64 + rl) * 128 + unit * 16;  // + mf*2048 at use
  }
#pragma unroll
  for (int nf2 = 0; nf2 < 2; ++nf2) {
    const int n = wn * 64 + nf2 * 16 + rl;
    const int swz = ((n >> 2) ^ n) & 7;
#pragma unroll
    for (int ks = 0; ks < 2; ++ks)
      bbF[nf2][ks] = n * 128 + (((ks * 4 + kg) ^ swz) << 4);  // + (nf>>1)*4096 at use
  }

  f32x4 acc[4][4];
#pragma unroll
  for (int mf = 0; mf < 4; ++mf)
#pragma unroll
    for (int nf = 0; nf < 4; ++nf) acc[mf][nf] = (f32x4)(0.0f);

  const bool mact = (wm * 64) < ne;

  auto compute = [&](const char* Ab, const char* Bb) {
#pragma unroll
    for (int ks = 0; ks < 2; ++ks) {
      bf16x8 bfr[4];
#pragma unroll
      for (int nf = 0; nf < 4; ++nf)
        bfr[nf] = *reinterpret_cast<const bf16x8*>(Bb + bbF[nf & 1][ks] + (nf >> 1) * 4096);
#pragma unroll
      for (int mf = 0; mf < 4; ++mf) {
        bf16x8 af = *reinterpret_cast<const bf16x8*>(Ab + abyte[ks] + mf * 2048);
#pragma unroll
        for (int nf = 0; nf < 4; ++nf)
          acc[mf][nf] = __builtin_amdgcn_mfma_f32_16x16x32_bf16(af, bfr[nf], acc[mf][nf], 0, 0, 0);
      }
    }
  };

  f32x4 b0, b1, b2, b3;  // single B register set (rule #20: named, static)

#define LGKM0 asm volatile("s_waitcnt lgkmcnt(0)" ::: "memory")
#define VMW2  asm volatile("s_waitcnt vmcnt(2)" ::: "memory")
#define VMW6  asm volatile("s_waitcnt vmcnt(6)" ::: "memory")
#define BARRIER asm volatile("s_barrier" ::: "memory")
  // step T (entry invariant: in flight = [B(t+1):4 older, A(t+1):2]):
#define FSTEP(T, AB, BSR, BSW)            \
  {                                       \
    VMW2;              /* B(t+1) here */  \
    writeB(BSW, b0, b1, b2, b3);          \
    loadB((T) + 2, b0, b1, b2, b3);       \
    if (mact) compute(AB, BSR);           \
    LGKM0; BARRIER;                       \
    stageA((T) + 2, AB);                  \
    VMW6;              /* A(t+1) here */  \
    BARRIER;                              \
  }

  // ---- prologue ----
  loadB(0, b0, b1, b2, b3);
  stageA(0, Ab0);
  VMW2;                       // retire B(0), keep A(0)
  writeB(Bs0, b0, b1, b2, b3);
  loadB(1, b0, b1, b2, b3);
  stageA(1, Ab1);
  VMW6;                       // retire A(0); keep {B(1),A(1)}
  LGKM0; BARRIER;

  // ---- main loop: T = 0..NK-3 (30 steps) ----
  for (int t2 = 0; t2 < NK - 2; t2 += 2) {
    FSTEP(t2,     Ab0, Bs0, Bs1);
    FSTEP(t2 + 1, Ab1, Bs1, Bs0);
  }

  // ---- tail T = NK-2 (even), then NK-1 ----
  VMW2;                        // B(NK-1) arrived
  writeB(Bs1, b0, b1, b2, b3);
  if (mact) compute(Ab0, Bs0);
  LGKM0;
  asm volatile("s_waitcnt vmcnt(0)" ::: "memory");  // A(NK-1) landed
  BARRIER;
  if (mact) compute(Ab1, Bs1);
#undef FSTEP
#undef LGKM0
#undef VMW2
#undef VMW6
#undef BARRIER

  // ---- epilogue ----
  if (mact) {
    const int rg = (lane >> 4) * 4;
    float bc[4];
#pragma unroll
    for (int nf = 0; nf < 4; ++nf)
      bc[nf] = (MODE == 1 && kh != 0) ? 0.0f
             : bias[(long)e * NDIM + n0 + wn * 64 + nf * 16 + rl];
#pragma unroll
    for (int mf = 0; mf < 4; ++mf) {
#pragma unroll
      for (int r = 0; r < 4; ++r) {
        const int row = wm * 64 + mf * 16 + rg + r;
        if (row < ne) {
          const int gid = sgid[row];
#pragma unroll
          for (int nf = 0; nf < 4; ++nf) {
            const int col = n0 + wn * 64 + nf * 16 + rl;
            float v = acc[mf][nf][r] + bc[nf];
            if constexpr (MODE == 0) {
              v = fmaxf(v, 0.0f);
              Hout[(long)gid * NDIM + col] = f2bf(v);
            } else {
              v *= tw[gid];
              atomicAdd(Oout + (long)(gid >> 1) * NDIM + col, v);
            }
          }
        }
      }
    }
  }
}

extern "C" void kernel_launch(void* const* d_in, const int* in_sizes, int n_in,
                              void* d_out, int out_size, void* d_ws, size_t ws_size,
                              hipStream_t stream) {
  const float* tokens = (const float*)d_in[0];
  const int* idx      = (const int*)d_in[1];
  const float* tw     = (const float*)d_in[2];
  const float* w1     = (const float*)d_in[3];
  const float* b1     = (const float*)d_in[4];
  const float* w2     = (const float*)d_in[5];
  const float* b2     = (const float*)d_in[6];
  float* out = (float*)d_out;

  char* ws = (char*)d_ws;
  int* counts  = (int*)ws;
  int* gidlist = (int*)(ws + 1024);
  unsigned short* A1   = (unsigned short*)(ws + 32768);
  unsigned short* hbuf = (unsigned short*)(ws + 32768 + (size_t)NTOK * HID * 2);

  hipMemsetAsync(out, 0, (size_t)NTOK * HID * sizeof(float), stream);
  route_kernel<<<1, 256, 0, stream>>>(idx, counts, gidlist);
  prep_a_kernel<<<(NTOK * HID / 4) / 256, 256, 0, stream>>>(tokens, A1);

  hipFuncSetAttribute((const void*)moe_gemm_kernel<HID, INTER_D, 0, 1>,
                      hipFuncAttributeMaxDynamicSharedMemorySize, 131072);
  hipFuncSetAttribute((const void*)moe_gemm_kernel<INTER_D, HID, 1, 2>,
                      hipFuncAttributeMaxDynamicSharedMemorySize, 131072);

  // G1: 16 experts x 16 n-chunks = 256 blocks
  moe_gemm_kernel<HID, INTER_D, 0, 1><<<E_N * (INTER_D / 256), 1024, 131072, stream>>>(
      A1, w1, b1, nullptr, counts, gidlist, hbuf, nullptr);
  // G2: 16 experts x 8 n-chunks x 2 K-halves = 256 blocks
  moe_gemm_kernel<INTER_D, HID, 1, 2><<<E_N * (HID / 256) * 2, 1024, 131072, stream>>>(
      hbuf, w2, b2, tw, counts, gidlist, nullptr, out);
}